// Round 1
// baseline (529.594 us; speedup 1.0000x reference)
//
#include <hip/hip_runtime.h>

// Problem constants (match reference.py)
#define B_ 2
#define L_ 1024
#define M_ 8
#define N_ 16
#define C_ 16
#define H_ 64
#define W_ 64

#define NVOTE (M_ * N_)        // 128 votes per (b,l)
#define PLANE (H_ * W_)        // 4096 floats per channel plane (16 KiB)

typedef float vf4  __attribute__((ext_vector_type(4)));
typedef float vf16 __attribute__((ext_vector_type(16)));

// Raw barrier with LDS-only wait: never drains vmcnt, so global stores from
// earlier channels stay in flight across channel boundaries. __syncthreads()
// would emit s_waitcnt vmcnt(0) before s_barrier (the known full-drain stall).
// Safe: LDS-buffer reuse only requires the ds_read results to be in registers
// (lgkmcnt), not the global stores to have completed (vmcnt).
__device__ __forceinline__ void bar_nodrain() {
    asm volatile("s_waitcnt lgkmcnt(0)" ::: "memory");
    __builtin_amdgcn_s_barrier();
    asm volatile("" ::: "memory");
}

// One block per (b,l): bins computed ONCE (not 16x), all 16 channel weights
// loaded as one contiguous 64B vf16 per vote, then a fully-unrolled channel
// loop streams 16 planes out of a single 16 KiB LDS buffer with lgkm-only
// barriers. 2048 blocks = exactly 8 blocks/CU (16 KiB LDS, 32 waves) -> one
// residency wave, no dispatch tail.
__global__ __launch_bounds__(256, 8) void hough_vote_bl_kernel(
    const float* __restrict__ feats,       // [B,L,N,C] f32
    const int*   __restrict__ voxels_src,  // [B,L,2]   i32
    const int*   __restrict__ voxels_dst,  // [B,L,2]   i32
    const int*   __restrict__ idxs_src,    // [B,L,M]   i32
    const int*   __restrict__ idxs_dst,    // [B,L,N]   i32
    float*       __restrict__ out)         // [B,L,C,H,W] f32
{
    const int bl  = blockIdx.x;            // 0 .. B*L-1
    const int b   = bl >> 10;              // L == 1024
    const int tid = threadIdx.x;           // 0..255

    __shared__ float s_plane[PLANE];
    vf4* p4 = (vf4*)s_plane;

    // ---- Gather phase, once per (b,l): bin + 16 channel weights -----------
    // Index/voxel/feat tables total ~3 MB -> L2-resident. feats row for a
    // vote is 16 contiguous floats (64B, aligned) -> single vf16 load.
    int  bin = -1;
    vf16 wv;
    if (tid < NVOTE) {
        const int m    = tid >> 4;               // vote row   (0..7)
        const int n    = tid & (N_ - 1);         // vote col   (0..15)
        const int s    = idxs_src[bl * M_ + m];
        const int base = b * L_ + s;
        const int2 vs  = ((const int2*)voxels_src)[base];
        const int  dd  = idxs_dst[base * N_ + n];
        const int2 vd  = ((const int2*)voxels_dst)[b * L_ + dd];
        wv = *(const vf16*)(feats + ((size_t)base * N_ + n) * C_);
        // voxels are ints: floor(float diff) == int diff exactly
        const int by = vd.x - vs.x + H_ / 2;
        const int bx = vd.y - vs.y + W_ / 2;
        if (by >= 0 && by < H_ && bx >= 0 && bx < W_)
            bin = by * W_ + bx;
    }

    // ---- Zero the plane once (overlaps the gather load chain above) -------
    const vf4 z = {0.f, 0.f, 0.f, 0.f};
    #pragma unroll
    for (int i = 0; i < PLANE / 4 / 256; ++i)
        p4[i * 256 + tid] = z;
    bar_nodrain();

    vf4* o4base = (vf4*)(out + (size_t)bl * C_ * PLANE);

    // ---- Channel loop: scatter -> store+clear, 2 lgkm-only barriers each --
    // Fully unrolled so wv[c] is a static vector extract (stays in VGPRs).
    #pragma unroll
    for (int c = 0; c < C_; ++c) {
        if (bin >= 0) atomicAdd(&s_plane[bin], wv[c]);
        bar_nodrain();                      // atomics visible to all waves

        vf4* o4 = o4base + c * (PLANE / 4);
        #pragma unroll
        for (int i = 0; i < PLANE / 4 / 256; ++i) {
            const int idx = i * 256 + tid;
            vf4 v = p4[idx];                // ds_read_b128
            o4[idx] = v;                    // global_store_dwordx4 (coalesced)
            if (c < C_ - 1) p4[idx] = z;    // clear behind ourselves, in-order
        }
        bar_nodrain();                      // all reads+clears done -> reuse
    }
    // endpgm: stores drain in the background (no vmcnt(0) anywhere).
}

extern "C" void kernel_launch(void* const* d_in, const int* in_sizes, int n_in,
                              void* d_out, int out_size, void* d_ws, size_t ws_size,
                              hipStream_t stream) {
    const float* feats      = (const float*)d_in[0];
    const int*   voxels_src = (const int*)d_in[1];
    const int*   voxels_dst = (const int*)d_in[2];
    const int*   idxs_src   = (const int*)d_in[3];
    const int*   idxs_dst   = (const int*)d_in[4];
    float*       out        = (float*)d_out;

    hough_vote_bl_kernel<<<B_ * L_, 256, 0, stream>>>(
        feats, voxels_src, voxels_dst, idxs_src, idxs_dst, out);
}